// Round 3
// baseline (11987.577 us; speedup 1.0000x reference)
//
#include <hip/hip_runtime.h>
#include <hip/hip_bf16.h>

// gNet: 4-layer graph net, B=1, HID=128, N=50000, E=500000.
// Inputs/outputs fp32 (per reference). Internal edge-activations bf16,
// LN stats fp64 via deterministic two-pass reduction.

typedef __hip_bfloat16 bf16;

#define HSTEP 0.1f

__device__ __forceinline__ float b2f(bf16 v){ return __bfloat162float(v); }
__device__ __forceinline__ bf16  f2b(float v){ return __float2bfloat16(v); }
__device__ __forceinline__ unsigned int f2bu(float v){
    return (unsigned int)__builtin_bit_cast(unsigned short, __float2bfloat16(v));
}

// store 8 fp32 as 8 bf16 (one 16B store)
__device__ __forceinline__ void store8(bf16* p, const float* a){
    uint4 q;
    q.x = f2bu(a[0]) | (f2bu(a[1]) << 16);
    q.y = f2bu(a[2]) | (f2bu(a[3]) << 16);
    q.z = f2bu(a[4]) | (f2bu(a[5]) << 16);
    q.w = f2bu(a[6]) | (f2bu(a[7]) << 16);
    *(uint4*)p = q;
}
__device__ __forceinline__ void store8(float* p, const float* a){
    *(float4*)p       = make_float4(a[0],a[1],a[2],a[3]);
    *((float4*)p + 1) = make_float4(a[4],a[5],a[6],a[7]);
}
__device__ __forceinline__ void stor1(bf16* p, float y){ *p = f2b(y); }
__device__ __forceinline__ void stor1(float* p, float y){ *p = y; }

// decode 4 bf16 (8B) -> float4
__device__ __forceinline__ float4 load4bf(const bf16* p){
    uint2 b = *(const uint2*)p;
    float4 q;
    q.x = __uint_as_float(b.x << 16);
    q.y = __uint_as_float(b.x & 0xffff0000u);
    q.z = __uint_as_float(b.y << 16);
    q.w = __uint_as_float(b.y & 0xffff0000u);
    return q;
}

// ---------------- weight prep (fp32 src) ----------------
__global__ void wt_transpose(const float* __restrict__ src, float* __restrict__ dst,
                             int O, int C) {
    int i = blockIdx.x*256 + threadIdx.x;
    if (i >= O*C) return;
    int o = i / C, c = i - o*C;
    dst[c*O + o] = src[i];
}

// KE1 [256][384] -> folded+transposed [256c][256o] (row==col==iInd)
__global__ void wt_ke1eff(const float* __restrict__ src, float* __restrict__ dst) {
    int i = blockIdx.x*256 + threadIdx.x;
    if (i >= 256*256) return;
    int o = i >> 8, c = i & 255;
    float v;
    if (c < 128) v = src[o*384 + c] + src[o*384 + 128 + c];
    else         v = src[o*384 + 128 + c];
    dst[c*256 + o] = v;
}

// ---------------- LN stat reduction (deterministic, no atomics) ----------------
__global__ void ln_reduce(const double* __restrict__ redp, int nb,
                          float* __restrict__ ln, double cnt)
{
    __shared__ double s0[256], s1[256];
    int tx = threadIdx.x;
    double a = 0.0, b = 0.0;
    for (int i = tx; i < nb; i += 256) { a += redp[2*i]; b += redp[2*i+1]; }
    s0[tx] = a; s1[tx] = b;
    __syncthreads();
    for (int s = 128; s > 0; s >>= 1) {
        if (tx < s) { s0[tx] += s0[tx+s]; s1[tx] += s1[tx+s]; }
        __syncthreads();
    }
    if (tx == 0) {
        double m = s0[0] / cnt;
        double var = s1[0] / cnt - m*m;
        if (var < 0.0) var = 0.0;
        ln[0] = (float)m;
        ln[1] = (float)(1.0 / sqrt(var + 1e-5));
    }
}

// ---------------- GEMM1: u = W1 @ v, + per-block sum/sumsq partials ----------------
enum { M1_OPEN = 0, M1_EDGE = 1, M1_NODE = 2 };

template<int OC, int IC, int MODE, typename OUT_T>
__launch_bounds__(256)
__global__ void mm1_kernel(const float* __restrict__ Wt,     // [IC][OC] fp32
                           const float* __restrict__ xin,    // OPEN: [IC][n] fp32 row-major
                           const float* __restrict__ xn_cm,  // [N][128] col-major
                           const float* __restrict__ xe_rm,  // [128][E] row-major
                           const float* __restrict__ si,     // [N][128] col-major
                           const float* __restrict__ sj,     // [N][128] col-major
                           const int*   __restrict__ iInd,
                           OUT_T* __restrict__ uout,         // [OC][n] row-major
                           int n, double* __restrict__ redp)
{
    constexpr int RPT = OC/32;
    constexpr int KC = 32, TN = 64;
    __shared__ float lv[KC][TN];
    __shared__ int lidx[TN];
    __shared__ double sred[512];
    const int tx = threadIdx.x;
    const int tr = tx & 31, tc = tx >> 5;
    const int x0 = blockIdx.x * TN;

    if constexpr (MODE == M1_EDGE) {
        if (tx < TN) lidx[tx] = (x0 + tx < n) ? iInd[x0 + tx] : 0;
    }
    __syncthreads();

    float acc[RPT][8];
    #pragma unroll
    for (int ri=0; ri<RPT; ++ri)
        #pragma unroll
        for (int ei=0; ei<8; ++ei) acc[ri][ei] = 0.f;

    for (int c0 = 0; c0 < IC; c0 += KC) {
        if constexpr (MODE == M1_OPEN) {
            // fp32 row-major [IC][n], float4 along x
            #pragma unroll
            for (int k=0; k<2; ++k) {
                int id = k*256 + tx;
                int xq = id & 15, cc = id >> 4;
                int x = x0 + xq*4;
                const float* p = xin + (size_t)(c0+cc)*n + x;
                float4 q;
                if (x + 3 < n) q = *(const float4*)p;
                else {
                    q.x = (x  <n)?p[0]:0.f; q.y = (x+1<n)?p[1]:0.f;
                    q.z = (x+2<n)?p[2]:0.f; q.w = (x+3<n)?p[3]:0.f;
                }
                *(float4*)&lv[cc][xq*4] = q;
            }
        } else if constexpr (MODE == M1_EDGE) {
            if (c0 < 128) {   // gathered node features (col-major, float4)
                #pragma unroll
                for (int k=0; k<2; ++k) {
                    int id = k*256 + tx;
                    int xx = id & 63, cg = id >> 6;
                    const float* p = xn_cm + (size_t)lidx[xx]*128 + c0 + cg*4;
                    float4 q = *(const float4*)p;
                    lv[cg*4+0][xx] = q.x; lv[cg*4+1][xx] = q.y;
                    lv[cg*4+2][xx] = q.z; lv[cg*4+3][xx] = q.w;
                }
            } else {          // edge features (row-major, float4 along x)
                #pragma unroll
                for (int k=0; k<2; ++k) {
                    int id = k*256 + tx;
                    int xq = id & 15, cc = id >> 4;
                    int x = x0 + xq*4;
                    const float* p = xe_rm + (size_t)(c0-128+cc)*n + x;
                    float4 q;
                    if (x + 3 < n) q = *(const float4*)p;
                    else {
                        q.x = (x  <n)?p[0]:0.f; q.y = (x+1<n)?p[1]:0.f;
                        q.z = (x+2<n)?p[2]:0.f; q.w = (x+3<n)?p[3]:0.f;
                    }
                    *(float4*)&lv[cc][xq*4] = q;
                }
            }
        } else {              // M1_NODE: [0.5*(si+sj); si-sj; xn] col-major
            #pragma unroll
            for (int k=0; k<2; ++k) {
                int id = k*256 + tx;
                int xx = id & 63, cg = id >> 6;
                int x = x0 + xx;
                int c = c0 + cg*4;
                float4 q;
                if (x < n) {
                    if (c0 < 128) {
                        float4 a = *(const float4*)(si + (size_t)x*128 + c);
                        float4 b = *(const float4*)(sj + (size_t)x*128 + c);
                        q.x = 0.5f*(a.x+b.x); q.y = 0.5f*(a.y+b.y);
                        q.z = 0.5f*(a.z+b.z); q.w = 0.5f*(a.w+b.w);
                    } else if (c0 < 256) {
                        float4 a = *(const float4*)(si + (size_t)x*128 + (c-128));
                        float4 b = *(const float4*)(sj + (size_t)x*128 + (c-128));
                        q.x = a.x-b.x; q.y = a.y-b.y; q.z = a.z-b.z; q.w = a.w-b.w;
                    } else {
                        q = *(const float4*)(xn_cm + (size_t)x*128 + (c-256));
                    }
                } else { q.x=q.y=q.z=q.w=0.f; }
                lv[cg*4+0][xx]=q.x; lv[cg*4+1][xx]=q.y;
                lv[cg*4+2][xx]=q.z; lv[cg*4+3][xx]=q.w;
            }
        }
        __syncthreads();
        for (int cc=0; cc<KC; ++cc) {
            const float* wrow = Wt + (size_t)(c0+cc)*OC + tr*RPT;
            float w[RPT];
            #pragma unroll
            for (int ri=0; ri<RPT; ++ri) w[ri] = wrow[ri];
            float vv[8];
            #pragma unroll
            for (int ei=0; ei<8; ++ei) vv[ei] = lv[cc][tc*8+ei];
            #pragma unroll
            for (int ri=0; ri<RPT; ++ri)
                #pragma unroll
                for (int ei=0; ei<8; ++ei)
                    acc[ri][ei] = fmaf(w[ri], vv[ei], acc[ri][ei]);
        }
        __syncthreads();
    }

    // ---- store u + per-block fp64 partial ----
    double ls = 0.0, ls2 = 0.0;
    const bool full = (x0 + TN <= n);
    if (full) {
        #pragma unroll
        for (int ri=0; ri<RPT; ++ri) {
            int r = tr*RPT + ri;
            store8(uout + (size_t)r*n + x0 + tc*8, acc[ri]);
            #pragma unroll
            for (int ei=0; ei<8; ++ei){ double y = acc[ri][ei]; ls += y; ls2 += y*y; }
        }
    } else {
        #pragma unroll
        for (int ri=0; ri<RPT; ++ri) {
            int r = tr*RPT + ri;
            #pragma unroll
            for (int ei=0; ei<8; ++ei) {
                int x = x0 + tc*8 + ei;
                if (x < n) {
                    float y = acc[ri][ei];
                    stor1(uout + (size_t)r*n + x, y);
                    ls += y; ls2 += (double)y*y;
                }
            }
        }
    }
    sred[tx] = ls; sred[256+tx] = ls2;
    __syncthreads();
    for (int s=128; s>0; s>>=1) {
        if (tx < s) { sred[tx] += sred[tx+s]; sred[256+tx] += sred[256+tx+s]; }
        __syncthreads();
    }
    if (tx == 0) {
        redp[2*(size_t)blockIdx.x]     = sred[0];
        redp[2*(size_t)blockIdx.x + 1] = sred[256];
    }
}

// ---------------- GEMM2: y = W2 @ relu((u-m)*rstd), fused epilogues ----------------
enum { IN_RM_BF16 = 0, IN_RM_F32 = 1, IN_CM_F32 = 2 };
enum { EPI_STORE_CM = 0, EPI_STORE_RM = 1, EPI_EDGE = 2, EPI_NODE = 3, EPI_OUT = 4 };

template<int OC, int IC, int INMODE, int EPI, bool LNRELU>
__launch_bounds__(256)
__global__ void mm2_kernel(const float* __restrict__ Wt,     // [IC][OC] fp32
                           const void*  __restrict__ uin,
                           const float* __restrict__ ln,     // {mean, rstd}
                           const int* __restrict__ iInd, const int* __restrict__ jInd,
                           float* __restrict__ dstA,         // xe_rm / xn_cm
                           float* __restrict__ si, float* __restrict__ sj,
                           float* __restrict__ outb,         // fp32 out (EPI_OUT)
                           int n)
{
    constexpr int RPT = OC/32;
    constexpr int KC = 32, TN = 64;
    __shared__ float lv[KC][TN];
    __shared__ int lidxI[TN], lidxJ[TN];
    const int tx = threadIdx.x;
    const int tr = tx & 31, tc = tx >> 5;
    const int x0 = blockIdx.x * TN;

    if constexpr (EPI == EPI_EDGE) {
        if (tx < TN) {
            int x = x0 + tx;
            lidxI[tx] = (x < n) ? iInd[x] : 0;
            lidxJ[tx] = (x < n) ? jInd[x] : 0;
        }
    }
    __syncthreads();

    float mean = 0.f, rstd = 1.f;
    if constexpr (LNRELU) { mean = ln[0]; rstd = ln[1]; }

    float acc[RPT][8];
    #pragma unroll
    for (int ri=0; ri<RPT; ++ri)
        #pragma unroll
        for (int ei=0; ei<8; ++ei) acc[ri][ei] = 0.f;

    for (int c0 = 0; c0 < IC; c0 += KC) {
        if constexpr (INMODE == IN_CM_F32) {
            #pragma unroll
            for (int k=0; k<2; ++k) {
                int id = k*256 + tx;
                int xx = id & 63, cg = id >> 6;
                int x = x0 + xx;
                float4 q;
                if (x < n) q = *(const float4*)((const float*)uin + (size_t)x*128 + c0 + cg*4);
                else { q.x=q.y=q.z=q.w=0.f; }
                if constexpr (LNRELU) {
                    q.x = fmaxf(0.f,(q.x-mean)*rstd); q.y = fmaxf(0.f,(q.y-mean)*rstd);
                    q.z = fmaxf(0.f,(q.z-mean)*rstd); q.w = fmaxf(0.f,(q.w-mean)*rstd);
                }
                lv[cg*4+0][xx]=q.x; lv[cg*4+1][xx]=q.y;
                lv[cg*4+2][xx]=q.z; lv[cg*4+3][xx]=q.w;
            }
        } else {
            #pragma unroll
            for (int k=0; k<2; ++k) {
                int id = k*256 + tx;
                int xq = id & 15, cc = id >> 4;
                int x = x0 + xq*4;
                int c = c0 + cc;
                float4 q;
                if constexpr (INMODE == IN_RM_F32) {
                    const float* p = (const float*)uin + (size_t)c*n + x;
                    if (x + 3 < n) q = *(const float4*)p;
                    else {
                        q.x = (x  <n)?p[0]:0.f; q.y = (x+1<n)?p[1]:0.f;
                        q.z = (x+2<n)?p[2]:0.f; q.w = (x+3<n)?p[3]:0.f;
                    }
                } else {
                    const bf16* p = (const bf16*)uin + (size_t)c*n + x;
                    if (x + 3 < n) q = load4bf(p);
                    else {
                        q.x = (x  <n)?b2f(p[0]):0.f; q.y = (x+1<n)?b2f(p[1]):0.f;
                        q.z = (x+2<n)?b2f(p[2]):0.f; q.w = (x+3<n)?b2f(p[3]):0.f;
                    }
                }
                if constexpr (LNRELU) {
                    q.x = fmaxf(0.f,(q.x-mean)*rstd); q.y = fmaxf(0.f,(q.y-mean)*rstd);
                    q.z = fmaxf(0.f,(q.z-mean)*rstd); q.w = fmaxf(0.f,(q.w-mean)*rstd);
                }
                *(float4*)&lv[cc][xq*4] = q;
            }
        }
        __syncthreads();
        for (int cc=0; cc<KC; ++cc) {
            const float* wrow = Wt + (size_t)(c0+cc)*OC + tr*RPT;
            float w[RPT];
            #pragma unroll
            for (int ri=0; ri<RPT; ++ri) w[ri] = wrow[ri];
            float vv[8];
            #pragma unroll
            for (int ei=0; ei<8; ++ei) vv[ei] = lv[cc][tc*8+ei];
            #pragma unroll
            for (int ri=0; ri<RPT; ++ri)
                #pragma unroll
                for (int ei=0; ei<8; ++ei)
                    acc[ri][ei] = fmaf(w[ri], vv[ei], acc[ri][ei]);
        }
        __syncthreads();
    }

    const bool full = (x0 + TN <= n);
    if constexpr (EPI == EPI_STORE_CM) {           // xn col-major, RPT==4
        #pragma unroll
        for (int ei=0; ei<8; ++ei) {
            int x = x0 + tc*8 + ei;
            if (x < n) {
                float4 q = make_float4(acc[0][ei],acc[1][ei],acc[2][ei],acc[3][ei]);
                *(float4*)(dstA + (size_t)x*128 + tr*4) = q;
            }
        }
    } else if constexpr (EPI == EPI_STORE_RM) {    // xe row-major
        if (full) {
            #pragma unroll
            for (int ri=0; ri<RPT; ++ri)
                store8(dstA + (size_t)(tr*RPT+ri)*n + x0 + tc*8, acc[ri]);
        } else {
            #pragma unroll
            for (int ri=0; ri<RPT; ++ri)
                #pragma unroll
                for (int ei=0; ei<8; ++ei) {
                    int x = x0 + tc*8 + ei;
                    if (x < n) dstA[(size_t)(tr*RPT+ri)*n + x] = acc[ri][ei];
                }
        }
    } else if constexpr (EPI == EPI_EDGE) {        // xe += h*y, scatter-add si/sj
        #pragma unroll
        for (int ri=0; ri<RPT; ++ri) {
            int r = tr*RPT + ri;
            if (full) {
                float* p = dstA + (size_t)r*n + x0 + tc*8;
                float4 a = *(float4*)p, b = *((float4*)p + 1);
                a.x += HSTEP*acc[ri][0]; a.y += HSTEP*acc[ri][1];
                a.z += HSTEP*acc[ri][2]; a.w += HSTEP*acc[ri][3];
                b.x += HSTEP*acc[ri][4]; b.y += HSTEP*acc[ri][5];
                b.z += HSTEP*acc[ri][6]; b.w += HSTEP*acc[ri][7];
                *(float4*)p = a; *((float4*)p + 1) = b;
            } else {
                #pragma unroll
                for (int ei=0; ei<8; ++ei) {
                    int x = x0 + tc*8 + ei;
                    if (x < n) dstA[(size_t)r*n + x] += HSTEP*acc[ri][ei];
                }
            }
            #pragma unroll
            for (int ei=0; ei<8; ++ei) {
                int xx = tc*8 + ei, x = x0 + xx;
                if (x < n) {
                    float y = acc[ri][ei];
                    unsafeAtomicAdd(si + (size_t)lidxI[xx]*128 + r, y);
                    unsafeAtomicAdd(sj + (size_t)lidxJ[xx]*128 + r, y);
                }
            }
        }
    } else if constexpr (EPI == EPI_NODE) {        // xn += h*y (col-major, RPT==4)
        #pragma unroll
        for (int ei=0; ei<8; ++ei) {
            int x = x0 + tc*8 + ei;
            if (x < n) {
                float* p = dstA + (size_t)x*128 + tr*4;
                float4 q = *(float4*)p;
                q.x += HSTEP*acc[0][ei]; q.y += HSTEP*acc[1][ei];
                q.z += HSTEP*acc[2][ei]; q.w += HSTEP*acc[3][ei];
                *(float4*)p = q;
            }
        }
    } else {                                       // EPI_OUT: fp32 row-major
        #pragma unroll
        for (int ri=0; ri<RPT; ++ri) {
            int r = tr*RPT + ri;
            if (full) {
                store8(outb + (size_t)r*n + x0 + tc*8, acc[ri]);
            } else {
                #pragma unroll
                for (int ei=0; ei<8; ++ei) {
                    int x = x0 + tc*8 + ei;
                    if (x < n) outb[(size_t)r*n + x] = acc[ri][ei];
                }
            }
        }
    }
}

extern "C" void kernel_launch(void* const* d_in, const int* in_sizes, int n_in,
                              void* d_out, int out_size, void* d_ws, size_t ws_size,
                              hipStream_t stream)
{
    const int N = in_sizes[0] / 32;          // 50000
    const int E = in_sizes[1] / 32;          // 500000
    const int NL = in_sizes[9] / (256*384);  // 4

    const float* xn_in = (const float*)d_in[0];
    const float* xe_in = (const float*)d_in[1];
    const int*   iInd  = (const int*)d_in[2];
    const int*   jInd  = (const int*)d_in[3];
    const float* K1N = (const float*)d_in[4];
    const float* K2N = (const float*)d_in[5];
    const float* K1E = (const float*)d_in[6];
    const float* K2E = (const float*)d_in[7];
    const float* KNo = (const float*)d_in[8];
    const float* KE1 = (const float*)d_in[9];
    const float* KE2 = (const float*)d_in[10];
    const float* KN1 = (const float*)d_in[11];
    const float* KN2 = (const float*)d_in[12];

    char* base = (char*)d_ws;
    size_t off = 0;
    auto carve = [&](size_t bytes)->void* {
        void* p = base + off; off += (bytes + 255) & ~(size_t)255; return p;
    };
    float* xn = (float*)carve((size_t)128*N*sizeof(float));   // col-major [N][128]
    float* xe = (float*)carve((size_t)128*E*sizeof(float));   // row-major [128][E]
    bf16*  u  = (bf16*) carve((size_t)256*E*sizeof(bf16));    // row-major [256][E]
    float* un = (float*)u;                                    // alias: node u [256][N] f32
    float* si = (float*)carve((size_t)128*N*sizeof(float));   // col-major
    float* sj = (float*)carve((size_t)128*N*sizeof(float));   // col-major
    float* wts= (float*)carve(300000*sizeof(float));
    double* redp = (double*)carve(2*8192*sizeof(double));     // per-block LN partials
    float* lnp = (float*)carve(256);

    if (ws_size < off) return;

    float* K1Nt = wts;                 // [32][128]
    float* K2Nt = K1Nt + 32*128;       // [128][128]
    float* K1Et = K2Nt + 128*128;      // [32][128]
    float* K2Et = K1Et + 32*128;       // [128][128]
    float* KNoT = K2Et + 128*128;      // [128][64]
    float* KE1t = KNoT + 128*64;       // [256][256]
    float* KE2t = KE1t + 256*256;      // [256][128]
    float* KN1t = KE2t + 256*128;      // [384][256]
    float* KN2t = KN1t + 384*256;      // [256][128]

    wt_transpose<<<dim3((128*32 +255)/256),dim3(256),0,stream>>>(K1N, K1Nt, 128, 32);
    wt_transpose<<<dim3((128*128+255)/256),dim3(256),0,stream>>>(K2N, K2Nt, 128, 128);
    wt_transpose<<<dim3((128*32 +255)/256),dim3(256),0,stream>>>(K1E, K1Et, 128, 32);
    wt_transpose<<<dim3((128*128+255)/256),dim3(256),0,stream>>>(K2E, K2Et, 128, 128);
    wt_transpose<<<dim3((64*128 +255)/256),dim3(256),0,stream>>>(KNo, KNoT, 64, 128);

    const int gN = (N + 63)/64, gE = (E + 63)/64;

    // ---- opening: nodes ----
    mm1_kernel<128,32,M1_OPEN,bf16><<<gN,256,0,stream>>>(
        K1Nt, xn_in, nullptr, nullptr, nullptr, nullptr, nullptr, u, N, redp);
    ln_reduce<<<1,256,0,stream>>>(redp, gN, lnp, 128.0*N);
    mm2_kernel<128,128,IN_RM_BF16,EPI_STORE_CM,true><<<gN,256,0,stream>>>(
        K2Nt, u, lnp, nullptr, nullptr, xn, nullptr, nullptr, nullptr, N);

    // ---- opening: edges ----
    mm1_kernel<128,32,M1_OPEN,bf16><<<gE,256,0,stream>>>(
        K1Et, xe_in, nullptr, nullptr, nullptr, nullptr, nullptr, u, E, redp);
    ln_reduce<<<1,256,0,stream>>>(redp, gE, lnp, 128.0*E);
    mm2_kernel<128,128,IN_RM_BF16,EPI_STORE_RM,true><<<gE,256,0,stream>>>(
        K2Et, u, lnp, nullptr, nullptr, xe, nullptr, nullptr, nullptr, E);

    for (int l = 0; l < NL; ++l) {
        wt_ke1eff<<<dim3(256),dim3(256),0,stream>>>(KE1 + (size_t)l*256*384, KE1t);
        wt_transpose<<<dim3((128*256+255)/256),dim3(256),0,stream>>>(KE2 + (size_t)l*128*256, KE2t, 128, 256);
        wt_transpose<<<dim3((256*384+255)/256),dim3(256),0,stream>>>(KN1 + (size_t)l*256*384, KN1t, 256, 384);
        wt_transpose<<<dim3((128*256+255)/256),dim3(256),0,stream>>>(KN2 + (size_t)l*128*256, KN2t, 128, 256);

        // edge double_layer
        mm1_kernel<256,256,M1_EDGE,bf16><<<gE,256,0,stream>>>(
            KE1t, nullptr, xn, xe, nullptr, nullptr, iInd, u, E, redp);
        ln_reduce<<<1,256,0,stream>>>(redp, gE, lnp, 256.0*E);
        (void)hipMemsetAsync(si, 0, (size_t)128*N*sizeof(float), stream);
        (void)hipMemsetAsync(sj, 0, (size_t)128*N*sizeof(float), stream);
        mm2_kernel<128,256,IN_RM_BF16,EPI_EDGE,true><<<gE,256,0,stream>>>(
            KE2t, u, lnp, iInd, jInd, xe, si, sj, nullptr, E);

        // node double_layer
        mm1_kernel<256,384,M1_NODE,float><<<gN,256,0,stream>>>(
            KN1t, nullptr, xn, nullptr, si, sj, nullptr, un, N, redp);
        ln_reduce<<<1,256,0,stream>>>(redp, gN, lnp, 256.0*N);
        mm2_kernel<128,256,IN_RM_F32,EPI_NODE,true><<<gN,256,0,stream>>>(
            KN2t, un, lnp, nullptr, nullptr, xn, nullptr, nullptr, nullptr, N);
    }

    // ---- final: xn_out = KNout @ xn ; copy xe (already fp32 row-major) ----
    mm2_kernel<64,128,IN_CM_F32,EPI_OUT,false><<<gN,256,0,stream>>>(
        KNoT, xn, nullptr, nullptr, nullptr, nullptr, nullptr, nullptr, (float*)d_out, N);
    (void)hipMemcpyAsync((float*)d_out + (size_t)64*N, xe,
                         (size_t)128*E*sizeof(float), hipMemcpyDeviceToDevice, stream);
}